// Round 1
// baseline (663.262 us; speedup 1.0000x reference)
//
#include <hip/hip_runtime.h>

#define M_TOK 8192
#define N_OUT 4096
#define K_IN  4096
#define BK    64
#define NT    (K_IN / BK)   // 64 k-tiles; one quant group per B-tile row

typedef __bf16 bf16;
typedef bf16  bf16x4  __attribute__((ext_vector_type(4)));
typedef bf16  bf16x8  __attribute__((ext_vector_type(8)));
typedef float floatx4 __attribute__((ext_vector_type(4)));

__device__ __forceinline__ bf16 dec_code(int c, float s) {
    // clip(c-3, -3, 3) == min(c,6)-3 for c in 0..7
    int q = (c > 6 ? 6 : c) - 3;
    return (bf16)((float)q * s);
}

__global__ __launch_bounds__(256, 2)
void linear3bit_kernel(const float* __restrict__ x,
                       const int*   __restrict__ wq,
                       const float* __restrict__ wscale,
                       const float* __restrict__ bias,
                       float*       __restrict__ out)
{
    __shared__ bf16 As[128][BK];   // x tile, bf16
    __shared__ bf16 Bs[128][BK];   // dequantized W tile, bf16 (row = out-feature)

    const int t     = threadIdx.x;
    const int nBlk  = blockIdx.x;        // 0..31
    const int mBlk  = blockIdx.y;        // 0..63
    const int mBase = mBlk * 128;
    const int nBase = nBlk * 128;

    const int wave = t >> 6;
    const int lane = t & 63;
    const int quad = lane >> 4;
    const int r16  = lane & 15;
    const int wm   = wave & 1;           // 2x2 wave grid over the 128x128 tile
    const int wn   = wave >> 1;

    floatx4 acc[4][4];
#pragma unroll
    for (int i = 0; i < 4; ++i)
#pragma unroll
        for (int j = 0; j < 4; ++j)
            acc[i][j] = (floatx4){0.f, 0.f, 0.f, 0.f};

    // B staging: 128 groups/tile, 2 threads per group (32 codes = 12 packed
    // int32 "bytes" each)
    const int gl   = t >> 1;             // local group/row 0..127
    const int half = t & 1;              // which half of the group

    const float* xBase = x + (size_t)mBase * K_IN;

    float4 aReg[8];
    int4   bReg[3];
    float  sReg;

    // ---- global loads for k-tile kt into registers ----
    auto loadTile = [&](int kt) {
#pragma unroll
        for (int i = 0; i < 8; ++i) {
            int linear = i * 256 + t;
            int row    = linear >> 4;          // 16 float4 per 64-wide row
            int c4     = (linear & 15) << 2;
            aReg[i] = *(const float4*)(xBase + (size_t)row * K_IN + kt * BK + c4);
        }
        size_t g = (size_t)(nBase + gl) * 64 + kt;   // group = o*64 + k/64
        const int* wp = wq + g * 24 + half * 12;
        bReg[0] = *(const int4*)(wp);
        bReg[1] = *(const int4*)(wp + 4);
        bReg[2] = *(const int4*)(wp + 8);
        sReg = wscale[g];
    };

    // ---- decode/convert registers -> LDS ----
    auto stage = [&]() {
#pragma unroll
        for (int i = 0; i < 8; ++i) {
            int linear = i * 256 + t;
            int row    = linear >> 4;
            int c4     = (linear & 15) << 2;
            float4 v = aReg[i];
            bf16x4 h = { (bf16)v.x, (bf16)v.y, (bf16)v.z, (bf16)v.w };
            *(bf16x4*)(&As[row][c4]) = h;
        }
        const float s = sReg;
        int by[12] = { bReg[0].x, bReg[0].y, bReg[0].z, bReg[0].w,
                       bReg[1].x, bReg[1].y, bReg[1].z, bReg[1].w,
                       bReg[2].x, bReg[2].y, bReg[2].z, bReg[2].w };
#pragma unroll
        for (int tri = 0; tri < 4; ++tri) {
            int b0 = by[tri * 3 + 0];
            int b1 = by[tri * 3 + 1];
            int b2 = by[tri * 3 + 2];
            bf16x8 h;
            h[0] = dec_code(b0 & 7, s);
            h[1] = dec_code((b0 >> 3) & 7, s);
            h[2] = dec_code(((b0 >> 6) & 3) | ((b1 & 1) << 2), s);
            h[3] = dec_code((b1 >> 1) & 7, s);
            h[4] = dec_code((b1 >> 4) & 7, s);
            h[5] = dec_code(((b1 >> 7) & 1) | ((b2 & 3) << 1), s);
            h[6] = dec_code((b2 >> 2) & 7, s);
            h[7] = dec_code((b2 >> 5) & 7, s);
            *(bf16x8*)(&Bs[gl][half * 32 + tri * 8]) = h;
        }
    };

    // ---- MFMA over the staged tile (2 k-steps of 32) ----
    auto compute = [&]() {
#pragma unroll
        for (int ks = 0; ks < 2; ++ks) {
            bf16x8 af[4], bfr[4];
#pragma unroll
            for (int mi = 0; mi < 4; ++mi)
                af[mi] = *(const bf16x8*)(&As[wm * 64 + mi * 16 + r16][ks * 32 + quad * 8]);
#pragma unroll
            for (int ni = 0; ni < 4; ++ni)
                bfr[ni] = *(const bf16x8*)(&Bs[wn * 64 + ni * 16 + r16][ks * 32 + quad * 8]);
#pragma unroll
            for (int mi = 0; mi < 4; ++mi)
#pragma unroll
                for (int ni = 0; ni < 4; ++ni)
                    acc[mi][ni] = __builtin_amdgcn_mfma_f32_16x16x32_bf16(
                        af[mi], bfr[ni], acc[mi][ni], 0, 0, 0);
        }
    };

    loadTile(0);
    for (int kt = 0; kt < NT; ++kt) {
        __syncthreads();                 // prior compute done with LDS
        stage();
        __syncthreads();
        if (kt + 1 < NT) loadTile(kt + 1);   // loads in flight across MFMA
        compute();
    }

    // ---- epilogue: C/D layout col=lane&15, row=quad*4+reg; add bias ----
    const int colBase = nBase + wn * 64;
#pragma unroll
    for (int ni = 0; ni < 4; ++ni) {
        int col  = colBase + ni * 16 + r16;
        float bv = bias[col];
#pragma unroll
        for (int mi = 0; mi < 4; ++mi) {
            int row0 = mBase + wm * 64 + mi * 16 + quad * 4;
#pragma unroll
            for (int r = 0; r < 4; ++r)
                out[(size_t)(row0 + r) * N_OUT + col] = acc[mi][ni][r] + bv;
        }
    }
}

extern "C" void kernel_launch(void* const* d_in, const int* in_sizes, int n_in,
                              void* d_out, int out_size, void* d_ws, size_t ws_size,
                              hipStream_t stream) {
    const float* x      = (const float*)d_in[0];
    const int*   wq     = (const int*)d_in[1];
    const float* wscale = (const float*)d_in[2];
    const float* bias   = (const float*)d_in[3];
    float*       out    = (float*)d_out;

    dim3 grid(N_OUT / 128, M_TOK / 128);   // (32, 64)
    linear3bit_kernel<<<grid, dim3(256), 0, stream>>>(x, wq, wscale, bias, out);
}

// Round 2
// 484.497 us; speedup vs baseline: 1.3690x; 1.3690x over previous
//
#include <hip/hip_runtime.h>

#define M_TOK 8192
#define N_OUT 4096
#define K_IN  4096
#define BK    64
#define NT    (K_IN / BK)   // 64 k-tiles

typedef __bf16 bf16;
typedef bf16  bf16x4  __attribute__((ext_vector_type(4)));
typedef bf16  bf16x8  __attribute__((ext_vector_type(8)));
typedef float floatx4 __attribute__((ext_vector_type(4)));

__device__ __forceinline__ bf16 dec_code(int c, float s) {
    // clip(c-3, -3, 3) == min(c,6)-3 for c in 0..7
    int q = (c > 6 ? 6 : c) - 3;
    return (bf16)((float)q * s);
}

__device__ __forceinline__ void async_ld16(const bf16* g, const bf16* l) {
    __builtin_amdgcn_global_load_lds(
        (const __attribute__((address_space(1))) void*)g,
        (__attribute__((address_space(3))) void*)l,
        16, 0, 0);
}

// ---------------------------------------------------------------------------
// Phase 1a: dequantize W (3-bit groups) -> bf16 [N_OUT][K_IN], each group once
// ---------------------------------------------------------------------------
__global__ __launch_bounds__(256)
void dequant_kernel(const int* __restrict__ wq, const float* __restrict__ wscale,
                    bf16* __restrict__ W)
{
    int idx  = blockIdx.x * 256 + threadIdx.x;   // 0 .. 2*NUM_GROUPS-1
    int g    = idx >> 1;
    int half = idx & 1;
    const int* wp = wq + (size_t)g * 24 + half * 12;
    int4 r0 = *(const int4*)(wp);
    int4 r1 = *(const int4*)(wp + 4);
    int4 r2 = *(const int4*)(wp + 8);
    float s = wscale[g];
    int by[12] = { r0.x, r0.y, r0.z, r0.w, r1.x, r1.y, r1.z, r1.w,
                   r2.x, r2.y, r2.z, r2.w };
    bf16* dst = W + (size_t)g * 64 + half * 32;
#pragma unroll
    for (int tri = 0; tri < 4; ++tri) {
        int b0 = by[tri * 3 + 0];
        int b1 = by[tri * 3 + 1];
        int b2 = by[tri * 3 + 2];
        bf16x8 h;
        h[0] = dec_code(b0 & 7, s);
        h[1] = dec_code((b0 >> 3) & 7, s);
        h[2] = dec_code(((b0 >> 6) & 3) | ((b1 & 1) << 2), s);
        h[3] = dec_code((b1 >> 1) & 7, s);
        h[4] = dec_code((b1 >> 4) & 7, s);
        h[5] = dec_code(((b1 >> 7) & 1) | ((b2 & 3) << 1), s);
        h[6] = dec_code((b2 >> 2) & 7, s);
        h[7] = dec_code((b2 >> 5) & 7, s);
        *(bf16x8*)(dst + tri * 8) = h;
    }
}

// ---------------------------------------------------------------------------
// Phase 1b: convert x fp32 -> bf16, once
// ---------------------------------------------------------------------------
__global__ __launch_bounds__(256)
void cvt_kernel(const float* __restrict__ x, bf16* __restrict__ xb)
{
    size_t i = ((size_t)blockIdx.x * 256 + threadIdx.x) * 8;
    float4 a = *(const float4*)(x + i);
    float4 b = *(const float4*)(x + i + 4);
    bf16x8 h = { (bf16)a.x, (bf16)a.y, (bf16)a.z, (bf16)a.w,
                 (bf16)b.x, (bf16)b.y, (bf16)b.z, (bf16)b.w };
    *(bf16x8*)(xb + i) = h;
}

// ---------------------------------------------------------------------------
// Phase 2: bf16 B^T GEMM, m97 structure + XOR-swizzled LDS (conflict-free)
//   A [M][K] bf16 row-major, B [N][K] bf16 row-major, out fp32 [M][N] + bias
// ---------------------------------------------------------------------------
__global__ __launch_bounds__(256, 2)
void gemm_kernel(const bf16* __restrict__ A, const bf16* __restrict__ B,
                 const float* __restrict__ bias, float* __restrict__ out)
{
    // physical layout: phys_chunk p of row r holds logical chunk p ^ (r&7)
    __shared__ bf16 As[128][BK];
    __shared__ bf16 Bs[128][BK];

    const int t     = threadIdx.x;
    const int nBase = blockIdx.x * 128;
    const int mBase = blockIdx.y * 128;

    const int wave = t >> 6;
    const int lane = t & 63;
    const int quad = lane >> 4;
    const int r16  = lane & 15;
    const int wm   = wave & 1;
    const int wn   = wave >> 1;

    // staging: per wave, 32 rows of A and 32 rows of B; per inst: 8 rows x 8 chunks
    const int rr  = lane >> 3;           // row within 8-row slab
    const int cc  = lane & 7;            // physical chunk (lane*16 dest)
    const int lch = cc ^ rr;             // swizzled logical chunk to fetch

    const bf16* aBase = A + (size_t)(mBase + wave * 32 + rr) * K_IN + lch * 8;
    const bf16* bBase = B + (size_t)(nBase + wave * 32 + rr) * K_IN + lch * 8;
    const bf16* aLds  = &As[wave * 32][0] + lane * 8;   // lane*16 bytes
    const bf16* bLds  = &Bs[wave * 32][0] + lane * 8;

    floatx4 acc[4][4];
#pragma unroll
    for (int i = 0; i < 4; ++i)
#pragma unroll
        for (int j = 0; j < 4; ++j)
            acc[i][j] = (floatx4){0.f, 0.f, 0.f, 0.f};

    const int sw = r16 & 7;

    for (int kt = 0; kt < NT; ++kt) {
        __syncthreads();                 // previous compute done with LDS
#pragma unroll
        for (int j = 0; j < 4; ++j) {
            async_ld16(aBase + (size_t)j * 8 * K_IN + kt * BK, aLds + j * 8 * BK);
            async_ld16(bBase + (size_t)j * 8 * K_IN + kt * BK, bLds + j * 8 * BK);
        }
        __syncthreads();                 // vmcnt(0) drain: tile visible

#pragma unroll
        for (int ks = 0; ks < 2; ++ks) {
            bf16x8 af[4], bfr[4];
#pragma unroll
            for (int mi = 0; mi < 4; ++mi)
                af[mi] = *(const bf16x8*)(&As[wm * 64 + mi * 16 + r16]
                                            [((ks * 4 + quad) ^ sw) * 8]);
#pragma unroll
            for (int ni = 0; ni < 4; ++ni)
                bfr[ni] = *(const bf16x8*)(&Bs[wn * 64 + ni * 16 + r16]
                                             [((ks * 4 + quad) ^ sw) * 8]);
#pragma unroll
            for (int mi = 0; mi < 4; ++mi)
#pragma unroll
                for (int ni = 0; ni < 4; ++ni)
                    acc[mi][ni] = __builtin_amdgcn_mfma_f32_16x16x32_bf16(
                        af[mi], bfr[ni], acc[mi][ni], 0, 0, 0);
        }
    }

    const int colBase = nBase + wn * 64;
#pragma unroll
    for (int ni = 0; ni < 4; ++ni) {
        int col  = colBase + ni * 16 + r16;
        float bv = bias[col];
#pragma unroll
        for (int mi = 0; mi < 4; ++mi) {
            int row0 = mBase + wm * 64 + mi * 16 + quad * 4;
#pragma unroll
            for (int r = 0; r < 4; ++r)
                out[(size_t)(row0 + r) * N_OUT + col] = acc[mi][ni][r] + bv;
        }
    }
}

// ---------------------------------------------------------------------------
// Fallback: proven fused kernel (round-1, passed) if ws is too small
// ---------------------------------------------------------------------------
__global__ __launch_bounds__(256, 2)
void linear3bit_fused(const float* __restrict__ x,
                      const int*   __restrict__ wq,
                      const float* __restrict__ wscale,
                      const float* __restrict__ bias,
                      float*       __restrict__ out)
{
    __shared__ bf16 As[128][BK];
    __shared__ bf16 Bs[128][BK];

    const int t     = threadIdx.x;
    const int mBase = blockIdx.y * 128;
    const int nBase = blockIdx.x * 128;

    const int wave = t >> 6;
    const int lane = t & 63;
    const int quad = lane >> 4;
    const int r16  = lane & 15;
    const int wm   = wave & 1;
    const int wn   = wave >> 1;

    floatx4 acc[4][4];
#pragma unroll
    for (int i = 0; i < 4; ++i)
#pragma unroll
        for (int j = 0; j < 4; ++j)
            acc[i][j] = (floatx4){0.f, 0.f, 0.f, 0.f};

    const int gl   = t >> 1;
    const int half = t & 1;
    const float* xBase = x + (size_t)mBase * K_IN;

    float4 aReg[8];
    int4   bReg[3];
    float  sReg;

    auto loadTile = [&](int kt) {
#pragma unroll
        for (int i = 0; i < 8; ++i) {
            int linear = i * 256 + t;
            int row    = linear >> 4;
            int c4     = (linear & 15) << 2;
            aReg[i] = *(const float4*)(xBase + (size_t)row * K_IN + kt * BK + c4);
        }
        size_t g = (size_t)(nBase + gl) * 64 + kt;
        const int* wp = wq + g * 24 + half * 12;
        bReg[0] = *(const int4*)(wp);
        bReg[1] = *(const int4*)(wp + 4);
        bReg[2] = *(const int4*)(wp + 8);
        sReg = wscale[g];
    };

    auto stage = [&]() {
#pragma unroll
        for (int i = 0; i < 8; ++i) {
            int linear = i * 256 + t;
            int row    = linear >> 4;
            int c4     = (linear & 15) << 2;
            float4 v = aReg[i];
            bf16x4 h = { (bf16)v.x, (bf16)v.y, (bf16)v.z, (bf16)v.w };
            *(bf16x4*)(&As[row][c4]) = h;
        }
        const float s = sReg;
        int by[12] = { bReg[0].x, bReg[0].y, bReg[0].z, bReg[0].w,
                       bReg[1].x, bReg[1].y, bReg[1].z, bReg[1].w,
                       bReg[2].x, bReg[2].y, bReg[2].z, bReg[2].w };
#pragma unroll
        for (int tri = 0; tri < 4; ++tri) {
            int b0 = by[tri * 3 + 0];
            int b1 = by[tri * 3 + 1];
            int b2 = by[tri * 3 + 2];
            bf16x8 h;
            h[0] = dec_code(b0 & 7, s);
            h[1] = dec_code((b0 >> 3) & 7, s);
            h[2] = dec_code(((b0 >> 6) & 3) | ((b1 & 1) << 2), s);
            h[3] = dec_code((b1 >> 1) & 7, s);
            h[4] = dec_code((b1 >> 4) & 7, s);
            h[5] = dec_code(((b1 >> 7) & 1) | ((b2 & 3) << 1), s);
            h[6] = dec_code((b2 >> 2) & 7, s);
            h[7] = dec_code((b2 >> 5) & 7, s);
            *(bf16x8*)(&Bs[gl][half * 32 + tri * 8]) = h;
        }
    };

    auto compute = [&]() {
#pragma unroll
        for (int ks = 0; ks < 2; ++ks) {
            bf16x8 af[4], bfr[4];
#pragma unroll
            for (int mi = 0; mi < 4; ++mi)
                af[mi] = *(const bf16x8*)(&As[wm * 64 + mi * 16 + r16][ks * 32 + quad * 8]);
#pragma unroll
            for (int ni = 0; ni < 4; ++ni)
                bfr[ni] = *(const bf16x8*)(&Bs[wn * 64 + ni * 16 + r16][ks * 32 + quad * 8]);
#pragma unroll
            for (int mi = 0; mi < 4; ++mi)
#pragma unroll
                for (int ni = 0; ni < 4; ++ni)
                    acc[mi][ni] = __builtin_amdgcn_mfma_f32_16x16x32_bf16(
                        af[mi], bfr[ni], acc[mi][ni], 0, 0, 0);
        }
    };

    loadTile(0);
    for (int kt = 0; kt < NT; ++kt) {
        __syncthreads();
        stage();
        __syncthreads();
        if (kt + 1 < NT) loadTile(kt + 1);
        compute();
    }

    const int colBase = nBase + wn * 64;
#pragma unroll
    for (int ni = 0; ni < 4; ++ni) {
        int col  = colBase + ni * 16 + r16;
        float bv = bias[col];
#pragma unroll
        for (int mi = 0; mi < 4; ++mi) {
            int row0 = mBase + wm * 64 + mi * 16 + quad * 4;
#pragma unroll
            for (int r = 0; r < 4; ++r)
                out[(size_t)(row0 + r) * N_OUT + col] = acc[mi][ni][r] + bv;
        }
    }
}

extern "C" void kernel_launch(void* const* d_in, const int* in_sizes, int n_in,
                              void* d_out, int out_size, void* d_ws, size_t ws_size,
                              hipStream_t stream) {
    const float* x      = (const float*)d_in[0];
    const int*   wq     = (const int*)d_in[1];
    const float* wscale = (const float*)d_in[2];
    const float* bias   = (const float*)d_in[3];
    float*       out    = (float*)d_out;

    const size_t wBytes  = (size_t)N_OUT * K_IN * sizeof(bf16);   // 32 MiB
    const size_t xBytes  = (size_t)M_TOK * K_IN * sizeof(bf16);   // 64 MiB

    if (ws_size >= wBytes + xBytes) {
        bf16* Wb = (bf16*)d_ws;
        bf16* Xb = (bf16*)((char*)d_ws + wBytes);
        // 2*NUM_GROUPS threads = 524288 -> 2048 blocks
        dequant_kernel<<<2048, 256, 0, stream>>>(wq, wscale, Wb);
        // 33.5M elements / 8 per thread -> 16384 blocks
        cvt_kernel<<<16384, 256, 0, stream>>>(x, Xb);
        dim3 grid(N_OUT / 128, M_TOK / 128);   // (32, 64)
        gemm_kernel<<<grid, dim3(256), 0, stream>>>(Xb, Wb, bias, out);
    } else {
        dim3 grid(N_OUT / 128, M_TOK / 128);
        linear3bit_fused<<<grid, dim3(256), 0, stream>>>(x, wq, wscale, bias, out);
    }
}